// Round 16
// baseline (123.364 us; speedup 1.0000x reference)
//
#include <hip/hip_runtime.h>

// FDLT: out[b,m,o] = sum_i psiHat[b,m,i] * E[m][i][o]
//   E[m] = cm * X_parity(m) @ D[m]^T   (X = XFc even m, XFs odd m)
// BATCH=2048, B=128 (m), N=256 (i), O=128 (o)
//
// Kernel 1: e_kernel -> Bpack[m][t][cf][lane]·16B (MFMA fragment-packed).
// Kernel 2 (r16): M-SWEEP blocks to linearize the DRAM footprint. Block =
//   32 b-rows x 8 consecutive m; slab = one m. Per b-row the A-read stream
//   is an 8KB LINEAR run (vs r13's 1KB fragments at 128KB stride) and the
//   write stream a 4KB run — full DRAM pages instead of sub-page scatter
//   (the one variable never tested across r5-r15's ~3.2 TB/s plateau).
//   B (Bpack[m']) is reloaded per slab, prefetched one slab ahead into a
//   ping-pong register set (L2/L3-served). Pipeline/swizzle/epilogue =
//   verbatim r13/r15 template.

typedef __attribute__((ext_vector_type(8))) short short8;
typedef __attribute__((ext_vector_type(4))) float f32x4;

#define NBATCH 2048
#define NM 128
#define NI 256   // K dim (i / j)
#define NO 128   // output o dim
// Bpack per m: 8 t-steps x 8 cf x 64 lanes x 8 bf16 = 32768 shorts (64 KB)
#define BPACK_M 32768

#define BROWS 32   // b-rows per block
#define MGRP 8     // consecutive m per block (slabs)
#define ABUF 32768 // bytes per A slab buffer (32 rows x 1024 B)

#define GLB(p) ((const __attribute__((address_space(1))) void*)(p))
#define LDS(p) ((__attribute__((address_space(3))) void*)(p))

__device__ __forceinline__ unsigned short f2bf(float f) {
  // round-to-nearest-even fp32 -> bf16
  unsigned int u = __builtin_bit_cast(unsigned int, f);
  u += 0x7FFFu + ((u >> 16) & 1u);
  return (unsigned short)(u >> 16);
}

__device__ __forceinline__ short8 cvt8(float4 a, float4 b, float s) {
  short8 v;
  v[0] = (short)f2bf(s * a.x); v[1] = (short)f2bf(s * a.y);
  v[2] = (short)f2bf(s * a.z); v[3] = (short)f2bf(s * a.w);
  v[4] = (short)f2bf(s * b.x); v[5] = (short)f2bf(s * b.y);
  v[6] = (short)f2bf(s * b.z); v[7] = (short)f2bf(s * b.w);
  return v;
}

// ---------------- Kernel 1: E precompute -> fragment-packed Bpack ----------
__global__ __launch_bounds__(256) void e_kernel(
    const float* __restrict__ XFc, const float* __restrict__ XFs,
    const float* __restrict__ D, const float* __restrict__ cmp,
    unsigned short* __restrict__ Bpack)
{
  const int m = blockIdx.x >> 1;
  const int ihalf = blockIdx.x & 1;
  const int tid = threadIdx.x;
  const int lane = tid & 63;
  const int w = tid >> 6;
  const int lr = lane & 15;   // frag row (A) / col (B)
  const int lg = lane >> 4;   // k group
  const float cm = cmp[0];
  const float* __restrict__ Xp = (m & 1) ? XFs : XFc;
  const float* __restrict__ Dm = D + (size_t)m * (NO * NI);
  const int i0 = ihalf * 128 + w * 32;   // multiple of 32

  f32x4 acc[2][8];
#pragma unroll
  for (int a = 0; a < 2; a++)
#pragma unroll
    for (int b = 0; b < 8; b++) acc[a][b] = (f32x4)0.f;

  for (int kk = 0; kk < NI; kk += 32) {
    const int kb = kk + lg * 8;
    short8 af[2];
#pragma unroll
    for (int rf = 0; rf < 2; rf++) {
      const float* ap = Xp + (size_t)(i0 + rf * 16 + lr) * NI + kb;
      float4 x0 = *(const float4*)ap;
      float4 x1 = *(const float4*)(ap + 4);
      af[rf] = cvt8(x0, x1, cm);
    }
    short8 bf[8];
#pragma unroll
    for (int cf = 0; cf < 8; cf++) {
      const float* bp = Dm + (size_t)(cf * 16 + lr) * NI + kb;
      float4 x0 = *(const float4*)bp;
      float4 x1 = *(const float4*)(bp + 4);
      bf[cf] = cvt8(x0, x1, 1.0f);
    }
#pragma unroll
    for (int rf = 0; rf < 2; rf++)
#pragma unroll
      for (int cf = 0; cf < 8; cf++)
        acc[rf][cf] = __builtin_amdgcn_mfma_f32_16x16x32_bf16(
            af[rf], bf[cf], acc[rf][cf], 0, 0, 0);
  }

  // acc C/D: o = cf*16 + lr, i = i0 + rf*16 + lg*4 + reg.
  // Consumer layout: lane L of (t,cf) holds E[i = t*32 + (L>>4)*8 + j][o =
  // cf*16 + (L&15)], j=0..7. Our 4 regs are half of one 8-run:
  //   t = (i0 + rf*16) >> 5, L = ((2*rf + (lg>>1)) & 3)*16 + lr, j0 = (lg&1)*4
  unsigned short* Bm = Bpack + (size_t)m * BPACK_M;
#pragma unroll
  for (int rf = 0; rf < 2; rf++) {
    const int t = (i0 + rf * 16) >> 5;
    const int L = ((2 * rf + (lg >> 1)) & 3) * 16 + lr;
#pragma unroll
    for (int cf = 0; cf < 8; cf++) {
      ushort4 pk;
      pk.x = f2bf(acc[rf][cf][0]);
      pk.y = f2bf(acc[rf][cf][1]);
      pk.z = f2bf(acc[rf][cf][2]);
      pk.w = f2bf(acc[rf][cf][3]);
      *(ushort4*)(Bm + (size_t)(t * 8 + cf) * 512 + L * 8 + (lg & 1) * 4) = pk;
    }
  }
}

// ---------------- Kernel 2: main GEMM, m-sweep + ring-2 pipeline -----------
// grid: (NM/MGRP, NBATCH/BROWS) = (16, 64) = 1024 blocks. 256 threads = 4
// waves. Block: b-rows b0..b0+31, m = m0..m0+7 (slab = one m). Wave w owns
// o-quarter cf = {2w, 2w+1}, all 32 rows (2 row-groups of 16).
// A-LDS: ring of 2 x [32 rows][1024 B], 16B-unit XOR swizzle p = u^(r&15)
// on glds SOURCE, undone on ds_read (r13-verified). Ob: [32 rows][512 B],
// p = u^(row&7) (r15-verified). B: ping-pong reg sets, prefetch 1 slab ahead.
#define SB __builtin_amdgcn_sched_barrier(0)

__global__ __launch_bounds__(256, 2) void fdlt_main(
    const float* __restrict__ psiHat,
    const unsigned short* __restrict__ Bpack,
    float* __restrict__ out)
{
  __shared__ float As_f[2 * BROWS * 256];   // 64 KB
  __shared__ float Ob_f[BROWS * 128];       // 16 KB -> 80 KB total
  const int m0 = blockIdx.x * MGRP;
  const int b0 = blockIdx.y * BROWS;
  const int tid = threadIdx.x;
  const int lane = tid & 63;
  const int w = tid >> 6;
  const int lr = lane & 15;
  const int lg = lane >> 4;
  const int cfbase = w * 2;
  char* As = (char*)As_f;
  char* Ob = (char*)Ob_f;

  // ---- B loader: 16 x short8 into the given ping-pong set ----
  auto LOADB = [&](short8 (&bl)[8][2], int ms) {
    const unsigned short* Bm = Bpack + (size_t)(m0 + ms) * BPACK_M;
#pragma unroll
    for (int t = 0; t < 8; t++)
#pragma unroll
      for (int j = 0; j < 2; j++)
        bl[t][j] = *(const short8*)(
            Bm + (size_t)(t * 8 + cfbase + j) * 512 + lane * 8);
  };

  // ---- A staging: 8 glds/wave, each one full 1KB contiguous psiHat row;
  // consecutive slabs advance by 1KB within the same rows (linear runs) ----
  auto STAGE = [&](int ms) {
#pragma unroll
    for (int j = 0; j < 8; j++) {
      const int r = j * 4 + w;
      const int fofs = ((lane ^ (r & 15)) << 2);
      const float* src =
          psiHat + ((size_t)(b0 + r) * NM + (m0 + ms)) * NI + fofs;
      __builtin_amdgcn_global_load_lds(GLB(src),
                                       LDS(As + (ms & 1) * ABUF + r * 1024),
                                       16, 0, 0);
    }
  };

  short8 ballA[8][2], ballB[8][2];
  f32x4 acc[2][2];   // [row-group][j]

  // ---- one slab = one m ----
  auto SLAB = [&](int ms, short8 (&cur)[8][2], short8 (&nxt)[8][2]) {
    // 1. compute slab ms from A-buf(ms&1); zero VMEM in this phase
#pragma unroll
    for (int rg = 0; rg < 2; rg++)
#pragma unroll
      for (int j = 0; j < 2; j++) acc[rg][j] = (f32x4)0.f;
#pragma unroll
    for (int t = 0; t < 8; t++) {
      const int p0 = ((((t * 4 + lg) << 1) ^ lr) << 4);
#pragma unroll
      for (int rg = 0; rg < 2; rg++) {
        const char* Arow = As + (ms & 1) * ABUF + (rg * 16 + lr) * 1024;
        float4 x0 = *(const float4*)(Arow + p0);
        float4 x1 = *(const float4*)(Arow + (p0 ^ 16));
        short8 af = cvt8(x0, x1, 1.0f);
#pragma unroll
        for (int j = 0; j < 2; j++)
          acc[rg][j] = __builtin_amdgcn_mfma_f32_16x16x32_bf16(
              af, cur[t][j], acc[rg][j], 0, 0, 0);
      }
    }

    // 2. epilogue-1: acc -> Ob (XOR-swizzled p = u^(row&7))
#pragma unroll
    for (int rg = 0; rg < 2; rg++)
#pragma unroll
      for (int j = 0; j < 2; j++) {
        const int u = (cfbase + j) * 4 + (lr >> 2);
#pragma unroll
        for (int r = 0; r < 4; r++) {
          const int row = rg * 16 + lg * 4 + r;
          const int p = u ^ (row & 7);
          *(float*)(Ob + row * 512 + p * 16 + (lr & 3) * 4) = acc[rg][j][r];
        }
      }
    asm volatile("s_waitcnt lgkmcnt(0)" ::: "memory");
    SB;
    __builtin_amdgcn_s_barrier();   // Ob published; A-buf(ms&1) fully read
    SB;

    // 3. prefetch next slab's B into the other reg set
    if (ms + 1 < MGRP) LOADB(nxt, ms + 1);
    // 4. stage A slab ms+2 into the freed buffer
    if (ms + 2 < MGRP) STAGE(ms + 2);

    // 5. epilogue-2: Ob -> global, one dense 512B row-half per instr
#pragma unroll
    for (int i = 0; i < 4; i++) {
      const int c = i * 256 + tid;
      const int row = c >> 5;          // 0..31
      const int u = c & 31;            // 16B unit within 512B row
      const int p = u ^ (row & 7);
      float4 v = *(const float4*)(Ob + row * 512 + p * 16);
      *(float4*)(&out[((size_t)(b0 + row) * NM + (m0 + ms)) * NO + u * 4]) = v;
    }
    SB;

    // 6. counted vmcnt BEFORE barrier (never-drain; FIFO ledger):
    //   steady (ms+2<MGRP):
    //     [stageA(ms+1):8][stores(ms-1):4][ball(ms+1):16][stageA(ms+2):8]
    //     [stores(ms):4] -> keep 12 (retires stageA(ms+1)+ball(ms+1))
    //   ms==MGRP-2: [stageA(7):8][stores(5):4][ball(7):16][stores(6):4]
    //     -> keep 4
    if (ms + 1 < MGRP) {
      if (ms + 2 < MGRP)
        asm volatile("s_waitcnt vmcnt(12)" ::: "memory");
      else
        asm volatile("s_waitcnt vmcnt(4)" ::: "memory");
      SB;
      __builtin_amdgcn_s_barrier();   // stageA(ms+1) visible; Ob reusable
      SB;
    }
  };

  // ---- prologue ----
  LOADB(ballA, 0);
  STAGE(0);
  STAGE(1);
  // FIFO: ballA[16], stage0[8], stage1[8] -> keep 8 = stage(1)
  asm volatile("s_waitcnt vmcnt(8)" ::: "memory");
  SB;
  __builtin_amdgcn_s_barrier();   // all waves' stage(0) visible
  SB;

#pragma unroll
  for (int ms = 0; ms < MGRP; ms += 2) {
    SLAB(ms, ballA, ballB);
    SLAB(ms + 1, ballB, ballA);
  }
}

extern "C" void kernel_launch(void* const* d_in, const int* in_sizes, int n_in,
                              void* d_out, int out_size, void* d_ws, size_t ws_size,
                              hipStream_t stream) {
  const float* psiHat = (const float*)d_in[0];
  const float* cm     = (const float*)d_in[1];
  const float* XFc    = (const float*)d_in[2];
  const float* XFs    = (const float*)d_in[3];
  const float* D      = (const float*)d_in[4];
  float* out = (float*)d_out;
  unsigned short* Bpack = (unsigned short*)d_ws;  // 128*32768*2 = 8.39 MB

  e_kernel<<<256, 256, 0, stream>>>(XFc, XFs, D, cm, Bpack);
  fdlt_main<<<dim3(NM / MGRP, NBATCH / BROWS), 256, 0, stream>>>(
      psiHat, Bpack, out);
}

// Round 17
// 113.428 us; speedup vs baseline: 1.0876x; 1.0876x over previous
//
#include <hip/hip_runtime.h>

// FDLT: out[b,m,o] = sum_i psiHat[b,m,i] * E[m][i][o]
//   E[m] = cm * X_parity(m) @ D[m]^T   (X = XFc even m, XFs odd m)
// BATCH=2048, B=128 (m), N=256 (i), O=128 (o)
//
// Kernel 1: e_kernel -> Bpack[m][t][cf][lane]·16B (MFMA fragment-packed).
// Kernel 2 (r17): M-PAIR page-completion. Block = (m0, m0+1) x 128 b-rows,
//   8 slabs of 16 rows x 2 m. The two 1KB halves of each 2KB DRAM page
//   (psiHat[b][m0..m0+1][:]) are staged by back-to-back glds from the SAME
//   wave -> one page activation serves the full page (r11/r13 activated
//   every page twice from uncorrelated blocks). B for BOTH m register-
//   resident (wave w: m-half w&1, o-half w>>1; ball = 128 VGPR) -> no r16
//   B-reload cost. Pipeline/swizzle/ledger = r13 template.

typedef __attribute__((ext_vector_type(8))) short short8;
typedef __attribute__((ext_vector_type(4))) float f32x4;

#define NBATCH 2048
#define NM 128
#define NI 256   // K dim (i / j)
#define NO 128   // output o dim
// Bpack per m: 8 t-steps x 8 cf x 64 lanes x 8 bf16 = 32768 shorts (64 KB)
#define BPACK_M 32768

#define NSLAB 8
#define SLABROWS 16
#define ABUF 32768   // bytes per slab buffer (16 rows x 2 m x 1024 B)

#define GLB(p) ((const __attribute__((address_space(1))) void*)(p))
#define LDS(p) ((__attribute__((address_space(3))) void*)(p))

__device__ __forceinline__ unsigned short f2bf(float f) {
  // round-to-nearest-even fp32 -> bf16
  unsigned int u = __builtin_bit_cast(unsigned int, f);
  u += 0x7FFFu + ((u >> 16) & 1u);
  return (unsigned short)(u >> 16);
}

__device__ __forceinline__ short8 cvt8(float4 a, float4 b, float s) {
  short8 v;
  v[0] = (short)f2bf(s * a.x); v[1] = (short)f2bf(s * a.y);
  v[2] = (short)f2bf(s * a.z); v[3] = (short)f2bf(s * a.w);
  v[4] = (short)f2bf(s * b.x); v[5] = (short)f2bf(s * b.y);
  v[6] = (short)f2bf(s * b.z); v[7] = (short)f2bf(s * b.w);
  return v;
}

// ---------------- Kernel 1: E precompute -> fragment-packed Bpack ----------
__global__ __launch_bounds__(256) void e_kernel(
    const float* __restrict__ XFc, const float* __restrict__ XFs,
    const float* __restrict__ D, const float* __restrict__ cmp,
    unsigned short* __restrict__ Bpack)
{
  const int m = blockIdx.x >> 1;
  const int ihalf = blockIdx.x & 1;
  const int tid = threadIdx.x;
  const int lane = tid & 63;
  const int w = tid >> 6;
  const int lr = lane & 15;   // frag row (A) / col (B)
  const int lg = lane >> 4;   // k group
  const float cm = cmp[0];
  const float* __restrict__ Xp = (m & 1) ? XFs : XFc;
  const float* __restrict__ Dm = D + (size_t)m * (NO * NI);
  const int i0 = ihalf * 128 + w * 32;   // multiple of 32

  f32x4 acc[2][8];
#pragma unroll
  for (int a = 0; a < 2; a++)
#pragma unroll
    for (int b = 0; b < 8; b++) acc[a][b] = (f32x4)0.f;

  for (int kk = 0; kk < NI; kk += 32) {
    const int kb = kk + lg * 8;
    short8 af[2];
#pragma unroll
    for (int rf = 0; rf < 2; rf++) {
      const float* ap = Xp + (size_t)(i0 + rf * 16 + lr) * NI + kb;
      float4 x0 = *(const float4*)ap;
      float4 x1 = *(const float4*)(ap + 4);
      af[rf] = cvt8(x0, x1, cm);
    }
    short8 bf[8];
#pragma unroll
    for (int cf = 0; cf < 8; cf++) {
      const float* bp = Dm + (size_t)(cf * 16 + lr) * NI + kb;
      float4 x0 = *(const float4*)bp;
      float4 x1 = *(const float4*)(bp + 4);
      bf[cf] = cvt8(x0, x1, 1.0f);
    }
#pragma unroll
    for (int rf = 0; rf < 2; rf++)
#pragma unroll
      for (int cf = 0; cf < 8; cf++)
        acc[rf][cf] = __builtin_amdgcn_mfma_f32_16x16x32_bf16(
            af[rf], bf[cf], acc[rf][cf], 0, 0, 0);
  }

  // acc C/D: o = cf*16 + lr, i = i0 + rf*16 + lg*4 + reg.
  // Consumer layout: lane L of (t,cf) holds E[i = t*32 + (L>>4)*8 + j][o =
  // cf*16 + (L&15)], j=0..7. Our 4 regs are half of one 8-run:
  //   t = (i0 + rf*16) >> 5, L = ((2*rf + (lg>>1)) & 3)*16 + lr, j0 = (lg&1)*4
  unsigned short* Bm = Bpack + (size_t)m * BPACK_M;
#pragma unroll
  for (int rf = 0; rf < 2; rf++) {
    const int t = (i0 + rf * 16) >> 5;
    const int L = ((2 * rf + (lg >> 1)) & 3) * 16 + lr;
#pragma unroll
    for (int cf = 0; cf < 8; cf++) {
      ushort4 pk;
      pk.x = f2bf(acc[rf][cf][0]);
      pk.y = f2bf(acc[rf][cf][1]);
      pk.z = f2bf(acc[rf][cf][2]);
      pk.w = f2bf(acc[rf][cf][3]);
      *(ushort4*)(Bm + (size_t)(t * 8 + cf) * 512 + L * 8 + (lg & 1) * 4) = pk;
    }
  }
}

// ---------------- Kernel 2: main GEMM, m-pair ring-2 pipeline --------------
// grid: (NM/2, NBATCH/128) = (64, 16). 256 threads = 4 waves.
// Block: m-pair (m0, m0+1), b-rows bbase..+127 as 8 slabs of 16.
// Wave w: m-half mm = w&1, o-half oh = w>>1 (cf = oh*4 .. +3), all 16 rows.
// A-LDS: ring of 2 x [16 rows][2 m][1024 B]; 16B-unit XOR swizzle
// p = u ^ r on glds SOURCE (dest linear), undone on ds_read (r13-verified).
#define SB __builtin_amdgcn_sched_barrier(0)

__global__ __launch_bounds__(256, 2) void fdlt_main(
    const float* __restrict__ psiHat,
    const unsigned short* __restrict__ Bpack,
    float* __restrict__ out)
{
  __shared__ float As_f[2 * SLABROWS * 2 * 256];   // 64 KB -> 2 blocks/CU
  const int m0 = blockIdx.x * 2;
  const int tid = threadIdx.x;
  const int lane = tid & 63;
  const int w = tid >> 6;
  const int bbase = blockIdx.y * (NSLAB * SLABROWS);
  const int lr = lane & 15;
  const int lg = lane >> 4;
  const int mm = w & 1;        // this wave's m-half
  const int oh = w >> 1;       // this wave's o-half
  const int mw = m0 + mm;      // this wave's m
  char* As = (char*)As_f;

  // ---- B resident for the whole block: 32 x short8 = 128 VGPR ----
  const unsigned short* __restrict__ Bm = Bpack + (size_t)mw * BPACK_M;
  short8 ball[8][4];
#pragma unroll
  for (int t = 0; t < 8; t++)
#pragma unroll
    for (int j = 0; j < 4; j++)
      ball[t][j] = *(const short8*)(
          Bm + (size_t)(t * 8 + oh * 4 + j) * 512 + lane * 8);

  // ---- staging: 8 glds/wave = 4 rows x 2 m; the two 1KB m-halves of each
  // 2KB DRAM page issue back-to-back (page completion). Source swizzled
  // (unit l ^ r), dest linear (base + lane*16).
  auto STAGE = [&](int s) {
#pragma unroll
    for (int j = 0; j < 4; j++) {
      const int r = j * 4 + w;
      const int fofs = ((lane ^ (r & 15)) << 2);
      const float* src0 =
          psiHat + ((size_t)(bbase + s * SLABROWS + r) * NM + m0) * NI;
#pragma unroll
      for (int h = 0; h < 2; h++) {
        __builtin_amdgcn_global_load_lds(
            GLB(src0 + h * NI + fofs),
            LDS(As + (s & 1) * ABUF + (r * 2 + h) * 1024), 16, 0, 0);
      }
    }
  };

  f32x4 acc[4];

  STAGE(0);
  STAGE(1);
  // FIFO: ball[32], stage0[8], stage1[8] -> keep 8 = stage(1)
  asm volatile("s_waitcnt vmcnt(8)" ::: "memory");
  SB;
  __builtin_amdgcn_s_barrier();   // all waves' stage(0) visible
  SB;

  for (int s = 0; s < NSLAB; s++) {
    // ---- compute slab s from buf (s&1); zero VMEM in this phase ----
    // A row lr of this wave's m-half; r13 swizzle: logical unit v = (t*4+lg)*2
    // (+1), phys = v ^ lr.
    const char* Arow = As + (s & 1) * ABUF + (lr * 2 + mm) * 1024;
#pragma unroll
    for (int j = 0; j < 4; j++) acc[j] = (f32x4)0.f;
#pragma unroll
    for (int t = 0; t < 8; t++) {
      const int p0 = ((((t * 4 + lg) << 1) ^ lr) << 4);
      float4 x0 = *(const float4*)(Arow + p0);
      float4 x1 = *(const float4*)(Arow + (p0 ^ 16));
      short8 af = cvt8(x0, x1, 1.0f);
#pragma unroll
      for (int j = 0; j < 4; j++)
        acc[j] = __builtin_amdgcn_mfma_f32_16x16x32_bf16(
            af, ball[t][j], acc[j], 0, 0, 0);
    }

    // ---- store slab s: 16 dwords/lane to this wave's m ----
#pragma unroll
    for (int j = 0; j < 4; j++) {
      const int o = (oh * 4 + j) * 16 + lr;
#pragma unroll
      for (int r = 0; r < 4; r++) {
        const int b = bbase + s * SLABROWS + lg * 4 + r;
        out[((size_t)b * NM + mw) * NO + o] = acc[j][r];
      }
    }
    SB;

    // ---- maintenance: counted vmcnt BEFORE barrier (never-drain) ----
    // FIFO ledger at the vmcnt (oldest->youngest), steady:
    //   [stores(s-1):16][stage(s+1):8][stores(s):16][stage(s+2):8] -> keep 24
    //   (retires stage(s+1) + older)
    //   s+2>=NSLAB: [stores(s-1):16][stage(s+1):8][stores(s):16]   -> keep 16
    if (s + 1 < NSLAB) {
      __builtin_amdgcn_s_barrier();     // all readers done with buf (s&1)
      SB;
      if (s + 2 < NSLAB) {
        STAGE(s + 2);                   // overwrite buf (s&1)
        asm volatile("s_waitcnt vmcnt(24)" ::: "memory");
      } else {
        asm volatile("s_waitcnt vmcnt(16)" ::: "memory");
      }
      SB;
      __builtin_amdgcn_s_barrier();     // stage(s+1) visible to all waves
      SB;
    }
  }
}

extern "C" void kernel_launch(void* const* d_in, const int* in_sizes, int n_in,
                              void* d_out, int out_size, void* d_ws, size_t ws_size,
                              hipStream_t stream) {
  const float* psiHat = (const float*)d_in[0];
  const float* cm     = (const float*)d_in[1];
  const float* XFc    = (const float*)d_in[2];
  const float* XFs    = (const float*)d_in[3];
  const float* D      = (const float*)d_in[4];
  float* out = (float*)d_out;
  unsigned short* Bpack = (unsigned short*)d_ws;  // 128*32768*2 = 8.39 MB

  e_kernel<<<256, 256, 0, stream>>>(XFc, XFs, D, cm, Bpack);
  fdlt_main<<<dim3(NM / 2, NBATCH / (NSLAB * SLABROWS)), 256, 0, stream>>>(
      psiHat, Bpack, out);
}

// Round 18
// 106.038 us; speedup vs baseline: 1.1634x; 1.0697x over previous
//
#include <hip/hip_runtime.h>

// FDLT: out[b,m,o] = sum_i psiHat[b,m,i] * E[m][i][o]
//   E[m] = cm * X_parity(m) @ D[m]^T   (X = XFc even m, XFs odd m)
// BATCH=2048, B=128 (m), N=256 (i), O=128 (o)
//
// Kernel 1: e_kernel -> Bpack[m][t][cf][lane]·16B (MFMA fragment-packed).
//   r18: split over o-halves (grid 512, 2 blocks/CU) — each block computes
//   64 o-columns and reads only its half of D[m]; ~halves precompute time.
// Kernel 2: fdlt_main = r11 VERBATIM (session best, 105.2 us): never-drain
//   slab pipeline, block = one m x 512 b-rows as 16 slabs of 32; LDS 2x32KB
//   dbuf; B hoisted once into 128 VGPR; counted vmcnt BEFORE barrier.
//   (r12/r13/r15/r16/r17 variations all plateaued or regressed — the
//   ~4.2 TB/s mixed-stream delivery is structural for this layout.)

typedef __attribute__((ext_vector_type(8))) short short8;
typedef __attribute__((ext_vector_type(4))) float f32x4;

#define NBATCH 2048
#define NM 128
#define NI 256   // K dim (i / j)
#define NO 128   // output o dim
// Bpack per m: 8 t-steps x 8 cf x 64 lanes x 8 bf16 = 32768 shorts (64 KB)
#define BPACK_M 32768

#define NSLAB 16
#define SLABROWS 32
#define LDSBUF 32768   // bytes per slab buffer (32 rows x 1024 B)

#define GLB(p) ((const __attribute__((address_space(1))) void*)(p))
#define LDS(p) ((__attribute__((address_space(3))) void*)(p))

__device__ __forceinline__ unsigned short f2bf(float f) {
  // round-to-nearest-even fp32 -> bf16
  unsigned int u = __builtin_bit_cast(unsigned int, f);
  u += 0x7FFFu + ((u >> 16) & 1u);
  return (unsigned short)(u >> 16);
}

__device__ __forceinline__ short8 cvt8(float4 a, float4 b, float s) {
  short8 v;
  v[0] = (short)f2bf(s * a.x); v[1] = (short)f2bf(s * a.y);
  v[2] = (short)f2bf(s * a.z); v[3] = (short)f2bf(s * a.w);
  v[4] = (short)f2bf(s * b.x); v[5] = (short)f2bf(s * b.y);
  v[6] = (short)f2bf(s * b.z); v[7] = (short)f2bf(s * b.w);
  return v;
}

// ---------------- Kernel 1: E precompute -> fragment-packed Bpack ----------
// grid: 512 blocks (m = bx>>2, ihalf = (bx>>1)&1, oh = bx&1), 256 threads.
// Block computes 128(i at ihalf) x 64(o at oh); wave w takes i0 + w*32.
__global__ __launch_bounds__(256) void e_kernel(
    const float* __restrict__ XFc, const float* __restrict__ XFs,
    const float* __restrict__ D, const float* __restrict__ cmp,
    unsigned short* __restrict__ Bpack)
{
  const int m = blockIdx.x >> 2;
  const int ihalf = (blockIdx.x >> 1) & 1;
  const int oh = blockIdx.x & 1;
  const int tid = threadIdx.x;
  const int lane = tid & 63;
  const int w = tid >> 6;
  const int lr = lane & 15;   // frag row (A) / col (B)
  const int lg = lane >> 4;   // k group
  const float cm = cmp[0];
  const float* __restrict__ Xp = (m & 1) ? XFs : XFc;
  const float* __restrict__ Dm = D + (size_t)m * (NO * NI);
  const int i0 = ihalf * 128 + w * 32;   // multiple of 32

  f32x4 acc[2][4];
#pragma unroll
  for (int a = 0; a < 2; a++)
#pragma unroll
    for (int b = 0; b < 4; b++) acc[a][b] = (f32x4)0.f;

  for (int kk = 0; kk < NI; kk += 32) {
    const int kb = kk + lg * 8;
    short8 af[2];
#pragma unroll
    for (int rf = 0; rf < 2; rf++) {
      const float* ap = Xp + (size_t)(i0 + rf * 16 + lr) * NI + kb;
      float4 x0 = *(const float4*)ap;
      float4 x1 = *(const float4*)(ap + 4);
      af[rf] = cvt8(x0, x1, cm);
    }
    short8 bf[4];
#pragma unroll
    for (int j = 0; j < 4; j++) {
      const int cf = oh * 4 + j;
      const float* bp = Dm + (size_t)(cf * 16 + lr) * NI + kb;
      float4 x0 = *(const float4*)bp;
      float4 x1 = *(const float4*)(bp + 4);
      bf[j] = cvt8(x0, x1, 1.0f);
    }
#pragma unroll
    for (int rf = 0; rf < 2; rf++)
#pragma unroll
      for (int j = 0; j < 4; j++)
        acc[rf][j] = __builtin_amdgcn_mfma_f32_16x16x32_bf16(
            af[rf], bf[j], acc[rf][j], 0, 0, 0);
  }

  // acc C/D: o = cf*16 + lr, i = i0 + rf*16 + lg*4 + reg.
  // Consumer layout: lane L of (t,cf) holds E[i = t*32 + (L>>4)*8 + jj][o =
  // cf*16 + (L&15)], jj=0..7. Our 4 regs are half of one 8-run:
  //   t = (i0 + rf*16) >> 5, L = ((2*rf + (lg>>1)) & 3)*16 + lr, j0 = (lg&1)*4
  unsigned short* Bm = Bpack + (size_t)m * BPACK_M;
#pragma unroll
  for (int rf = 0; rf < 2; rf++) {
    const int t = (i0 + rf * 16) >> 5;
    const int L = ((2 * rf + (lg >> 1)) & 3) * 16 + lr;
#pragma unroll
    for (int j = 0; j < 4; j++) {
      const int cf = oh * 4 + j;
      ushort4 pk;
      pk.x = f2bf(acc[rf][j][0]);
      pk.y = f2bf(acc[rf][j][1]);
      pk.z = f2bf(acc[rf][j][2]);
      pk.w = f2bf(acc[rf][j][3]);
      *(ushort4*)(Bm + (size_t)(t * 8 + cf) * 512 + L * 8 + (lg & 1) * 4) = pk;
    }
  }
}

// ---------------- Kernel 2: main GEMM, never-drain slab pipeline (r11) -----
// grid: (NM fast, NBATCH/(NSLAB*SLABROWS)) = (128, 4). 256 threads = 4 waves.
// Block: one m, rows bbase..+511 as 16 slabs of 32. Wave w computes rows
// (w>>1)*16..+15 of each slab, o-half (w&1) (cf = (w&1)*4..+3).
// LDS: [2][32 rows][1024 B], 32B-unit XOR swizzle (unit ^= row&7) applied to
// glds SOURCE (dest linear) and undone on ds_read (rule #21).
#define SB __builtin_amdgcn_sched_barrier(0)

__global__ __launch_bounds__(256, 2) void fdlt_main(
    const float* __restrict__ psiHat,
    const unsigned short* __restrict__ Bpack,
    float* __restrict__ out)
{
  __shared__ float As_f[2 * SLABROWS * 256];   // 64 KB -> 2 blocks/CU
  const int m = blockIdx.x;
  const int tid = threadIdx.x;
  const int lane = tid & 63;
  const int w = tid >> 6;
  const int bbase = blockIdx.y * (NSLAB * SLABROWS);
  const int lr = lane & 15;
  const int lg = lane >> 4;
  const int cfbase = (w & 1) * 4;
  char* As = (char*)As_f;

  const unsigned short* __restrict__ Bm = Bpack + (size_t)m * BPACK_M;

  // ---- B resident for the whole block: 32 x short8 = 128 VGPR ----
  short8 ball[8][4];
#pragma unroll
  for (int t = 0; t < 8; t++)
#pragma unroll
    for (int j = 0; j < 4; j++)
      ball[t][j] =
          *(const short8*)(Bm + (size_t)(t * 8 + cfbase + j) * 512 + lane * 8);

  // ---- staging: 8 glds, each one full 1KB contiguous psiHat row ----
  // lane covers 16B-unit u; logical 32B-unit = u>>1, piece = u&1;
  // source float offset = (((u>>1) ^ (r&7)) << 3) + ((u&1) << 2).
  auto STAGE = [&](int buf, int s) {
#pragma unroll
    for (int j = 0; j < 8; j++) {
      const int r = j * 4 + w;
      const int fofs = ((((lane >> 1) ^ (r & 7)) << 3) + ((lane & 1) << 2));
      const float* src =
          psiHat + ((size_t)(bbase + s * SLABROWS + r) * NM + m) * NI + fofs;
      __builtin_amdgcn_global_load_lds(GLB(src), LDS(As + buf * LDSBUF + r * 1024),
                                       16, 0, 0);
    }
  };

  const int arow = (w >> 1) * 16 + lr;   // row-in-slab this lane reads
  const int rsw = lr & 7;                // == arow & 7
  f32x4 acc[4];

  STAGE(0, 0);
  STAGE(1, 1);
  // retire own B-preload(32) + own stage(0)(8); keep stage(1)(8) in flight
  asm volatile("s_waitcnt vmcnt(8)" ::: "memory");
  SB;
  __builtin_amdgcn_s_barrier();   // all waves' stage(0) now visible
  SB;

  for (int s = 0; s < NSLAB; s++) {
    // ---- compute slab s from buf (s&1); zero VMEM in this phase ----
    const char* Arow = As + (s & 1) * LDSBUF + arow * 1024;
#pragma unroll
    for (int j = 0; j < 4; j++) acc[j] = (f32x4)0.f;
#pragma unroll
    for (int t = 0; t < 8; t++) {
      const int p = ((t * 4 + lg) ^ rsw) << 5;
      float4 x0 = *(const float4*)(Arow + p);
      float4 x1 = *(const float4*)(Arow + p + 16);
      short8 af = cvt8(x0, x1, 1.0f);
#pragma unroll
      for (int j = 0; j < 4; j++)
        acc[j] = __builtin_amdgcn_mfma_f32_16x16x32_bf16(
            af, ball[t][j], acc[j], 0, 0, 0);
    }

    // ---- store slab s: 16 dwords/lane (fire-and-forget) ----
#pragma unroll
    for (int j = 0; j < 4; j++) {
      const int o = (cfbase + j) * 16 + lr;
#pragma unroll
      for (int r = 0; r < 4; r++) {
        const int b = bbase + s * SLABROWS + (w >> 1) * 16 + lg * 4 + r;
        out[((size_t)b * NM + m) * NO + o] = acc[j][r];
      }
    }

    // ---- pipeline maintenance: vmcnt BEFORE barrier (per-wave counters,
    //      cross-wave LDS production) ----
    if (s + 1 < NSLAB) {
      __builtin_amdgcn_s_barrier();       // all readers done with buf(s&1)
      if (s + 2 < NSLAB) {
        STAGE((s + 2) & 1, s + 2);        // overwrite buf(s&1)
        // FIFO retire: leaves youngest 24 = stores(s)[16] + stage(s+2)[8];
        // everything older (incl. own stage(s+1)) retired.
        asm volatile("s_waitcnt vmcnt(24)" ::: "memory");
      } else {
        // leaves youngest 16 = stores(s); own stage(s+1) retired.
        asm volatile("s_waitcnt vmcnt(16)" ::: "memory");
      }
      SB;
      __builtin_amdgcn_s_barrier();       // stage(s+1) visible to all waves
      SB;
    }
  }
}

extern "C" void kernel_launch(void* const* d_in, const int* in_sizes, int n_in,
                              void* d_out, int out_size, void* d_ws, size_t ws_size,
                              hipStream_t stream) {
  const float* psiHat = (const float*)d_in[0];
  const float* cm     = (const float*)d_in[1];
  const float* XFc    = (const float*)d_in[2];
  const float* XFs    = (const float*)d_in[3];
  const float* D      = (const float*)d_in[4];
  float* out = (float*)d_out;
  unsigned short* Bpack = (unsigned short*)d_ws;  // 128*32768*2 = 8.39 MB

  e_kernel<<<512, 256, 0, stream>>>(XFc, XFs, D, cm, Bpack);
  fdlt_main<<<dim3(NM, NBATCH / (NSLAB * SLABROWS)), 256, 0, stream>>>(
      psiHat, Bpack, out);
}